// Round 14
// baseline (165.887 us; speedup 1.0000x reference)
//
#include <hip/hip_runtime.h>
#include <hip/hip_bf16.h>
#include <math.h>

// Problem dims
#define NB 2
#define NN 2048
#define FD 64
#define NH 4
#define HIDD 128
#define ROWS_TOT (NB*NN)   // 4096

// ws layout (float offsets). Total 1,720,320 floats = 6.88 MB.
#define XP_OFF   0
#define ES_OFF   524288
#define EN_OFF   540672
#define CU_OFF   557056
#define TBF_OFF  1081344   // bf16 t  [4096][128]
#define HPBF_OFF 1343488   // bf16 h' [4096][128]
// prep: fragment-ordered bf16 hi/lo weights: [jt][ks][lane] bf16x8
#define WUH_OFF  1605632
#define WUL_OFF  1622016
#define WRH_OFF  1638400
#define WRL_OFF  1654784
#define WCH_OFF  1671168
#define WCL_OFF  1687552
#define RPH_OFF  1703936
#define RPL_OFF  1712128

#define A_ELEMS (NB*NN*NN)

typedef __attribute__((ext_vector_type(8))) short bf16x8;
typedef __attribute__((ext_vector_type(8))) unsigned short ushort8;
typedef __attribute__((ext_vector_type(4))) unsigned short ushort4v;
typedef __attribute__((ext_vector_type(4))) float f32x4;

#define MFMA_BF16(a,b,c) __builtin_amdgcn_mfma_f32_16x16x32_bf16((a),(b),(c),0,0,0)

static __device__ inline unsigned short f2bf(float x) {
  __hip_bfloat16 b = __float2bfloat16(x);
  unsigned short u; __builtin_memcpy(&u, &b, 2); return u;
}
static __device__ inline float bf2f(unsigned short u) {
  __hip_bfloat16 b; __builtin_memcpy(&b, &u, 2); return __bfloat162float(b);
}
static __device__ inline void split2(float x, unsigned short& hi, unsigned short& lo) {
  hi = f2bf(x);
  lo = f2bf(x - bf2f(hi));
}

// ---------------------------------------------------------------------------
// k01: fused prep (blocks 0..447) + xp/es/en (blocks 448..959). (r12)
// ---------------------------------------------------------------------------
__global__ __launch_bounds__(256) void k01_prep_xp(
    const float* __restrict__ Wu, const float* __restrict__ Wr,
    const float* __restrict__ Wc, const float* __restrict__ Rp,
    unsigned short* __restrict__ wuh, unsigned short* __restrict__ wul,
    unsigned short* __restrict__ wrh, unsigned short* __restrict__ wrl,
    unsigned short* __restrict__ wch, unsigned short* __restrict__ wcl,
    unsigned short* __restrict__ rph, unsigned short* __restrict__ rpl,
    const float* __restrict__ x, const float* __restrict__ kern,
    const float* __restrict__ as_, const float* __restrict__ an_,
    float* __restrict__ xp, float* __restrict__ es, float* __restrict__ en)
{
  __shared__ float xr[8][FD];
  const int t = threadIdx.x;
  if (blockIdx.x < 448) {
    const int gid = blockIdx.x*256 + t;
    if (gid < 98304) {             // Wu/Wr/Wc: K=256 -> KS=8
      const int which = gid >> 15;
      const int loc = gid & 32767;
      const int e  = loc & 7;
      const int ln = (loc >> 3) & 63;
      const int ks = (loc >> 9) & 7;
      const int jt = loc >> 12;
      const int j = jt*16 + (ln & 15);
      const int k = ks*32 + ((ln >> 4) << 3) + e;
      const float* W = which == 0 ? Wu : (which == 1 ? Wr : Wc);
      unsigned short* oh = which == 0 ? wuh : (which == 1 ? wrh : wch);
      unsigned short* ol = which == 0 ? wul : (which == 1 ? wrl : wcl);
      unsigned short h, l; split2(W[k*128 + j], h, l);
      oh[loc] = h; ol[loc] = l;
    } else if (gid < 114688) {     // Rp: K=128 -> KS=4
      const int loc = gid - 98304;
      const int e  = loc & 7;
      const int ln = (loc >> 3) & 63;
      const int ks = (loc >> 9) & 3;
      const int jt = loc >> 11;
      const int j = jt*16 + (ln & 15);
      const int k = ks*32 + ((ln >> 4) << 3) + e;
      unsigned short h, l; split2(Rp[k*128 + j], h, l);
      rph[loc] = h; rpl[loc] = l;
    }
    return;
  }
  // ---- k1 part ----
  const int row0 = (blockIdx.x - 448) * 8;
  for (int idx = t; idx < 8*FD; idx += 256)
    xr[idx >> 6][idx & 63] = x[(size_t)row0*FD + idx];
  __syncthreads();
  const int c4 = (t & 31) * 4;
  const int rq = t >> 5;
  const float4 asv = *(const float4*)(as_ + c4);
  const float4 anv = *(const float4*)(an_ + c4);
  float4 acc = make_float4(0.f, 0.f, 0.f, 0.f);
#pragma unroll 8
  for (int f = 0; f < FD; ++f) {
    const float4 kv = *(const float4*)(kern + f*128 + c4);
    const float xv = xr[rq][f];
    acc.x = fmaf(xv, kv.x, acc.x);
    acc.y = fmaf(xv, kv.y, acc.y);
    acc.z = fmaf(xv, kv.z, acc.z);
    acc.w = fmaf(xv, kv.w, acc.w);
  }
  const int grow = row0 + rq;
  *(float4*)(xp + (size_t)grow*128 + c4) = acc;
  float s  = acc.x*asv.x + acc.y*asv.y + acc.z*asv.z + acc.w*asv.w;
  float n_ = acc.x*anv.x + acc.y*anv.y + acc.z*anv.z + acc.w*anv.w;
#pragma unroll
  for (int mk = 4; mk >= 1; mk >>= 1) {
    s  += __shfl_xor(s,  mk, 64);
    n_ += __shfl_xor(n_, mk, 64);
  }
  if ((t & 7) == 0) {
    const int h = (t & 31) >> 3;
    es[grow*NH + h] = s; en[grow*NH + h] = n_;
  }
}

// ---------------------------------------------------------------------------
// k2: sparse masked softmax + aggregation, wave-per-row. (unchanged)
// IDEMPOTENT: reads a/xp/es/en/bias, writes only cu.
// ---------------------------------------------------------------------------
__global__ __launch_bounds__(256) void k2_attn(
    const float* __restrict__ a, const float* __restrict__ xp,
    const float* __restrict__ es, const float* __restrict__ en,
    const float* __restrict__ bias, float* __restrict__ cu)
{
  __shared__ unsigned short sidx[4][NN];   // 16 KB
  __shared__ float swl[4][64][NH];         // 4 KB
  const int t = threadIdx.x;
  const int ln = t & 63, wv = t >> 6;
  const int row = blockIdx.x * 4 + wv;
  const int b = row >> 11;
  const float4 esi = *(const float4*)(es + (size_t)row*NH);

  int deg = 0;
  const float4* arow4 = (const float4*)(a + (size_t)row*NN);
#pragma unroll
  for (int cch = 0; cch < 8; ++cch) {
    const float4 v = arow4[cch*64 + ln];
    const int j0 = cch*256 + ln*4;
    const float vv[4] = {v.x, v.y, v.z, v.w};
#pragma unroll
    for (int q = 0; q < 4; ++q) {
      const unsigned long long m = __ballot(vv[q] > 0.5f);
      if (vv[q] > 0.5f) {
        const int pos = deg + (int)__popcll(m & ((1ull << ln) - 1ull));
        sidx[wv][pos] = (unsigned short)(j0 + q);
      }
      deg += (int)__popcll(m);
    }
  }

  const int col0 = ln, col1 = ln + 64;
  const int h0 = ln >> 5;
  float m0=-1e30f, m1=-1e30f, m2=-1e30f, m3=-1e30f;
  float s0=0.f, s1=0.f, s2=0.f, s3=0.f;
  float acc0=0.f, acc1=0.f;
  for (int base = 0; base < deg; base += 64) {
    const int rem = min(64, deg - base);
    float t0=-1e30f, t1=-1e30f, t2=-1e30f, t3=-1e30f;
    if (ln < rem) {
      const int j = sidx[wv][base + ln];
      const float4 e4 = *(const float4*)(en + (size_t)(b*NN + j)*NH);
      t0 = esi.x + e4.x; t0 = t0 > 0.f ? t0 : 0.2f*t0;
      t1 = esi.y + e4.y; t1 = t1 > 0.f ? t1 : 0.2f*t1;
      t2 = esi.z + e4.z; t2 = t2 > 0.f ? t2 : 0.2f*t2;
      t3 = esi.w + e4.w; t3 = t3 > 0.f ? t3 : 0.2f*t3;
    }
    float c0=t0, c1=t1, c2=t2, c3=t3;
#pragma unroll
    for (int mk = 32; mk >= 1; mk >>= 1) {
      c0 = fmaxf(c0, __shfl_xor(c0, mk));
      c1 = fmaxf(c1, __shfl_xor(c1, mk));
      c2 = fmaxf(c2, __shfl_xor(c2, mk));
      c3 = fmaxf(c3, __shfl_xor(c3, mk));
    }
    const float nm0 = fmaxf(m0,c0), nm1 = fmaxf(m1,c1);
    const float nm2 = fmaxf(m2,c2), nm3 = fmaxf(m3,c3);
    const float r0 = expf(m0-nm0), r1 = expf(m1-nm1);
    const float r2 = expf(m2-nm2), r3 = expf(m3-nm3);
    s0 *= r0; s1 *= r1; s2 *= r2; s3 *= r3;
    float w0=0.f, w1=0.f, w2=0.f, w3=0.f;
    if (ln < rem) {
      w0 = expf(t0-nm0); w1 = expf(t1-nm1);
      w2 = expf(t2-nm2); w3 = expf(t3-nm3);
    }
    float u0=w0, u1=w1, u2=w2, u3=w3;
#pragma unroll
    for (int mk = 32; mk >= 1; mk >>= 1) {
      u0 += __shfl_xor(u0, mk);
      u1 += __shfl_xor(u1, mk);
      u2 += __shfl_xor(u2, mk);
      u3 += __shfl_xor(u3, mk);
    }
    s0 += u0; s1 += u1; s2 += u2; s3 += u3;
    acc0 *= (h0 ? r1 : r0);
    acc1 *= (h0 ? r3 : r2);
    swl[wv][ln][0] = w0; swl[wv][ln][1] = w1;
    swl[wv][ln][2] = w2; swl[wv][ln][3] = w3;
#pragma unroll 4
    for (int k = 0; k < rem; ++k) {
      const int j = sidx[wv][base + k];
      const float* xr = xp + (size_t)(b*NN + j)*128;
      acc0 = fmaf(swl[wv][k][h0],     xr[col0], acc0);
      acc1 = fmaf(swl[wv][k][2 + h0], xr[col1], acc1);
    }
    m0=nm0; m1=nm1; m2=nm2; m3=nm3;
  }
  const float den0 = h0 ? s1 : s0;
  const float den1 = h0 ? s3 : s2;
  cu[(size_t)row*128 + col0] = acc0/den0 + bias[col0];
  cu[(size_t)row*128 + col1] = acc1/den1 + bias[col1];
}

// ---------------------------------------------------------------------------
// k3: fused GRU gates + t = h'@R_p via 3-term split-bf16 MFMA. (r12, 16-wave)
// ---------------------------------------------------------------------------
__global__ __launch_bounds__(1024) void k3_mfma(
    const float* __restrict__ cu_, const float* __restrict__ hin,
    const float* __restrict__ bu, const float* __restrict__ br,
    const float* __restrict__ bc,
    const unsigned short* __restrict__ wuh, const unsigned short* __restrict__ wul,
    const unsigned short* __restrict__ wrh, const unsigned short* __restrict__ wrl,
    const unsigned short* __restrict__ wch, const unsigned short* __restrict__ wcl,
    const unsigned short* __restrict__ rph, const unsigned short* __restrict__ rpl,
    float* __restrict__ hp_out,
    __hip_bfloat16* __restrict__ hp_bf, __hip_bfloat16* __restrict__ t_bf)
{
  __shared__ __align__(16) char zH[16*512];
  __shared__ __align__(16) char zL[16*512];
  __shared__ __align__(16) char red[32768];
  char* rhH  = red;
  char* rhL  = red + 4096;
  char* hpH  = red + 8192;
  char* hpLo = red + 12288;
  float* redA = (float*)red;
  float* redB = (float*)(red + 16384);
  const int t = threadIdx.x;
  const int row0 = blockIdx.x * 16;

  {
    const int q = t;
    const int r = q >> 6;
    const int c = (q & 63) * 4;
    float4 v;
    if (c < 128) v = *(const float4*)(cu_ + (size_t)(row0+r)*128 + c);
    else         v = *(const float4*)(hin + (size_t)(row0+r)*128 + (c-128));
    unsigned short hx, lx, hy, ly, hz, lz, hw, lw;
    split2(v.x, hx, lx); split2(v.y, hy, ly);
    split2(v.z, hz, lz); split2(v.w, hw, lw);
    ushort4v h4; h4[0]=hx; h4[1]=hy; h4[2]=hz; h4[3]=hw;
    ushort4v l4; l4[0]=lx; l4[1]=ly; l4[2]=lz; l4[3]=lw;
    const int byte = (c*2) ^ ((r & 7) << 4);
    *(ushort4v*)(zH + r*512 + byte) = h4;
    *(ushort4v*)(zL + r*512 + byte) = l4;
  }
  __syncthreads();                                   // B1

  const int ln = t & 63, w = t >> 6;
  const int jt = w & 7, half = w >> 3;
  const int lr = ln & 15, kid = ln >> 4;
  const int sw = (lr & 7) << 4;
  const int colg = jt*16 + lr;
  const f32x4 zero = {0.f, 0.f, 0.f, 0.f};
  const bf16x8* wuhF = (const bf16x8*)wuh;
  const bf16x8* wulF = (const bf16x8*)wul;
  const bf16x8* wrhF = (const bf16x8*)wrh;
  const bf16x8* wrlF = (const bf16x8*)wrl;
  const bf16x8* wchF = (const bf16x8*)wch;
  const bf16x8* wclF = (const bf16x8*)wcl;
  const bf16x8* rphF = (const bf16x8*)rph;
  const bf16x8* rplF = (const bf16x8*)rpl;

  f32x4 accU = zero, accR = zero;
#pragma unroll
  for (int i = 0; i < 4; ++i) {
    const int ks = half*4 + i;
    const int kb = ks*64 + kid*16;
    const bf16x8 ah = *(const bf16x8*)(zH + lr*512 + (kb ^ sw));
    const bf16x8 al = *(const bf16x8*)(zL + lr*512 + (kb ^ sw));
    const int fb = (jt*8 + ks)*64 + ln;
    const bf16x8 buH = wuhF[fb];
    const bf16x8 buL = wulF[fb];
    const bf16x8 brH = wrhF[fb];
    const bf16x8 brL = wrlF[fb];
    accU = MFMA_BF16(ah, buH, accU);
    accU = MFMA_BF16(ah, buL, accU);
    accU = MFMA_BF16(al, buH, accU);
    accR = MFMA_BF16(ah, brH, accR);
    accR = MFMA_BF16(ah, brL, accR);
    accR = MFMA_BF16(al, brH, accR);
  }
  *(f32x4*)(redA + w*256 + ln*4) = accU;
  *(f32x4*)(redB + w*256 + ln*4) = accR;
  __syncthreads();                                   // B2

  float hval[4], uval[4];
  if (half == 0) {
    accU += *(const f32x4*)(redA + (w+8)*256 + ln*4);
    accR += *(const f32x4*)(redB + (w+8)*256 + ln*4);
#pragma unroll
    for (int reg = 0; reg < 4; ++reg) {
      const int row16 = kid*4 + reg;
      const int grow = row0 + row16;
      const int nrow = grow & (NN-1);
      const float h_ = hin[(size_t)grow*128 + colg];
      const float uv = 1.f/(1.f + expf(-(bu[nrow] + accU[reg])));
      const float rv = 1.f/(1.f + expf(-(br[nrow] + accR[reg])));
      hval[reg] = h_; uval[reg] = uv;
      unsigned short hs, ls; split2(rv * h_, hs, ls);
      const int byte = (colg*2) ^ ((row16 & 7) << 4);
      *(unsigned short*)(rhH + row16*256 + byte) = hs;
      *(unsigned short*)(rhL + row16*256 + byte) = ls;
    }
  }
  __syncthreads();                                   // B3

  f32x4 accC = zero;
#pragma unroll
  for (int i = 0; i < 4; ++i) {
    const int kb = i*64 + kid*16;
    bf16x8 ah, al;
    if (half == 0) {
      ah = *(const bf16x8*)(zH + lr*512 + (kb ^ sw));
      al = *(const bf16x8*)(zL + lr*512 + (kb ^ sw));
    } else {
      ah = *(const bf16x8*)(rhH + lr*256 + (kb ^ sw));
      al = *(const bf16x8*)(rhL + lr*256 + (kb ^ sw));
    }
    const int ks = half*4 + i;
    const int fb = (jt*8 + ks)*64 + ln;
    const bf16x8 bH = wchF[fb];
    const bf16x8 bL = wclF[fb];
    accC = MFMA_BF16(ah, bH, accC);
    accC = MFMA_BF16(ah, bL, accC);
    accC = MFMA_BF16(al, bH, accC);
  }
  *(f32x4*)(redB + w*256 + ln*4) = accC;
  __syncthreads();                                   // B4

  if (half == 0) {
    accC += *(const f32x4*)(redB + (w+8)*256 + ln*4);
#pragma unroll
    for (int reg = 0; reg < 4; ++reg) {
      const int row16 = kid*4 + reg;
      const int grow = row0 + row16;
      const int nrow = grow & (NN-1);
      const float cc = tanhf(bc[nrow] + accC[reg]);
      const float uv = uval[reg];
      const float hpv = uv*hval[reg] + (1.f - uv)*cc;
      hp_out[(size_t)grow*128 + colg] = hpv;
      hp_bf[(size_t)grow*128 + colg] = __float2bfloat16(hpv);
      unsigned short hs, ls; split2(hpv, hs, ls);
      const int byte = (colg*2) ^ ((row16 & 7) << 4);
      *(unsigned short*)(hpH  + row16*256 + byte) = hs;
      *(unsigned short*)(hpLo + row16*256 + byte) = ls;
    }
  }
  __syncthreads();                                   // B5

  f32x4 accT = zero;
#pragma unroll
  for (int i = 0; i < 2; ++i) {
    const int ks = half*2 + i;
    const int kb = ks*64 + kid*16;
    const bf16x8 ah = *(const bf16x8*)(hpH  + lr*256 + (kb ^ sw));
    const bf16x8 al = *(const bf16x8*)(hpLo + lr*256 + (kb ^ sw));
    const int fb = (jt*4 + ks)*64 + ln;
    const bf16x8 bH = rphF[fb];
    const bf16x8 bL = rplF[fb];
    accT = MFMA_BF16(ah, bH, accT);
    accT = MFMA_BF16(ah, bL, accT);
    accT = MFMA_BF16(al, bH, accT);
  }
  *(f32x4*)(redB + w*256 + ln*4) = accT;
  __syncthreads();                                   // B6

  if (half == 0) {
    accT += *(const f32x4*)(redB + (w+8)*256 + ln*4);
#pragma unroll
    for (int reg = 0; reg < 4; ++reg) {
      const int grow = row0 + kid*4 + reg;
      t_bf[(size_t)grow*128 + colg] = __float2bfloat16(accT[reg]);
    }
  }
}

// ---------------------------------------------------------------------------
// k4b: A[b] = t[b] @ hp[b]^T via bf16 MFMA + LDS-transposed coalesced
// writeout. (unchanged from r11) IDEMPOTENT: writes only A.
// ---------------------------------------------------------------------------
__global__ __launch_bounds__(256) void k4b_dec(
    const __hip_bfloat16* __restrict__ t_bf,
    const __hip_bfloat16* __restrict__ hp_bf,
    float* __restrict__ A)
{
  __shared__ __align__(16) char smem[128*132*4];  // 67.5 KB
  char* Alds = smem;
  char* Blds = smem + 32768;
  float* Cst = (float*)smem;
  const int t = threadIdx.x;
  const int ln = t & 63, wv = t >> 6;
  const int b = blockIdx.z;
  const int i0 = blockIdx.y * 128, j0 = blockIdx.x * 128;

  {
    const int sub = ln >> 4;
    const int cb  = (ln & 15) * 16;
#pragma unroll
    for (int q = 0; q < 8; ++q) {
      const int chunk = wv*8 + q;
      const int row = chunk*4 + sub;
      const int scb = cb ^ ((row & 7) << 4);
      const ushort8 va = *(const ushort8*)
          ((const char*)(t_bf + ((size_t)(b*NN) + i0 + row)*128) + cb);
      *(ushort8*)(Alds + row*256 + scb) = va;
      const ushort8 vb = *(const ushort8*)
          ((const char*)(hp_bf + ((size_t)(b*NN) + j0 + row)*128) + cb);
      *(ushort8*)(Blds + row*256 + scb) = vb;
    }
  }
  __syncthreads();

  const int wr = wv >> 1, wc = wv & 1;
  const int lrow = ln & 15;
  const int kid  = ln >> 4;
  f32x4 acc[4][4];
  const f32x4 zero = {0.f, 0.f, 0.f, 0.f};
#pragma unroll
  for (int m = 0; m < 4; ++m)
#pragma unroll
    for (int n = 0; n < 4; ++n) acc[m][n] = zero;

#pragma unroll
  for (int ks = 0; ks < 4; ++ks) {
    const int kb = ks*64 + kid*16;
    bf16x8 af[4], bfr[4];
#pragma unroll
    for (int m = 0; m < 4; ++m) {
      const int arow = wr*64 + m*16 + lrow;
      af[m] = *(const bf16x8*)(Alds + arow*256 + (kb ^ ((arow & 7) << 4)));
      const int brow = wc*64 + m*16 + lrow;
      bfr[m] = *(const bf16x8*)(Blds + brow*256 + (kb ^ ((brow & 7) << 4)));
    }
#pragma unroll
    for (int m = 0; m < 4; ++m)
#pragma unroll
      for (int n = 0; n < 4; ++n)
        acc[m][n] = MFMA_BF16(af[m], bfr[n], acc[m][n]);
  }
  __syncthreads();

#pragma unroll
  for (int m = 0; m < 4; ++m) {
    const int crow = wr*64 + m*16 + kid*4;
#pragma unroll
    for (int n = 0; n < 4; ++n) {
      const int ccol = wc*64 + n*16 + lrow;
#pragma unroll
      for (int r = 0; r < 4; ++r)
        Cst[(crow + r)*132 + ccol] = acc[m][n][r];
    }
  }
  __syncthreads();

#pragma unroll
  for (int p = 0; p < 16; ++p) {
    const int row = p*8 + (t >> 5);
    const int c4  = (t & 31) * 4;
    const float4 v = *(const float4*)&Cst[row*132 + c4];
    *(float4*)(A + ((size_t)b*NN + i0 + row)*NN + j0 + c4) = v;
  }
}

// ---------------------------------------------------------------------------
extern "C" void kernel_launch(void* const* d_in, const int* in_sizes, int n_in,
                              void* d_out, int out_size, void* d_ws, size_t ws_size,
                              hipStream_t stream)
{
  const float* x    = (const float*)d_in[0];
  const float* a    = (const float*)d_in[1];
  const float* h    = (const float*)d_in[2];
  const float* kern = (const float*)d_in[3];
  const float* as_  = (const float*)d_in[4];
  const float* an_  = (const float*)d_in[5];
  const float* bias = (const float*)d_in[6];
  const float* bu   = (const float*)d_in[7];
  const float* br   = (const float*)d_in[8];
  const float* bc   = (const float*)d_in[9];
  const float* Wu   = (const float*)d_in[10];
  const float* Wr   = (const float*)d_in[11];
  const float* Wc   = (const float*)d_in[12];
  const float* Rp   = (const float*)d_in[13];
  (void)in_sizes; (void)n_in; (void)out_size; (void)ws_size;

  float* ws = (float*)d_ws;
  float* xp = ws + XP_OFF;
  float* es = ws + ES_OFF;
  float* en = ws + EN_OFF;
  float* cu = ws + CU_OFF;
  __hip_bfloat16* t_bf  = (__hip_bfloat16*)(ws + TBF_OFF);
  __hip_bfloat16* hp_bf = (__hip_bfloat16*)(ws + HPBF_OFF);
  unsigned short* wuh = (unsigned short*)(ws + WUH_OFF);
  unsigned short* wul = (unsigned short*)(ws + WUL_OFF);
  unsigned short* wrh = (unsigned short*)(ws + WRH_OFF);
  unsigned short* wrl = (unsigned short*)(ws + WRL_OFF);
  unsigned short* wch = (unsigned short*)(ws + WCH_OFF);
  unsigned short* wcl = (unsigned short*)(ws + WCL_OFF);
  unsigned short* rph = (unsigned short*)(ws + RPH_OFF);
  unsigned short* rpl = (unsigned short*)(ws + RPL_OFF);

  float* A  = (float*)d_out;
  float* hp = (float*)d_out + A_ELEMS;

  hipLaunchKernelGGL(k01_prep_xp, dim3(448 + ROWS_TOT/8), dim3(256), 0, stream,
                     Wu, Wr, Wc, Rp, wuh, wul, wrh, wrl, wch, wcl, rph, rpl,
                     x, kern, as_, an_, xp, es, en);
  // ATTRIBUTION PROBE: k2 and k4b launched twice (idempotent).
  // dur delta vs r12 = k2_warm + k4b_warm.
  hipLaunchKernelGGL(k2_attn, dim3(ROWS_TOT/4), dim3(256), 0, stream,
                     a, xp, es, en, bias, cu);
  hipLaunchKernelGGL(k2_attn, dim3(ROWS_TOT/4), dim3(256), 0, stream,
                     a, xp, es, en, bias, cu);
  hipLaunchKernelGGL(k3_mfma, dim3(ROWS_TOT/16), dim3(1024), 0, stream,
                     cu, h, bu, br, bc, wuh, wul, wrh, wrl, wch, wcl, rph, rpl,
                     hp, hp_bf, t_bf);
  hipLaunchKernelGGL(k4b_dec, dim3(NN/128, NN/128, NB), dim3(256), 0, stream,
                     t_bf, hp_bf, A);
  hipLaunchKernelGGL(k4b_dec, dim3(NN/128, NN/128, NB), dim3(256), 0, stream,
                     t_bf, hp_bf, A);
}